// Round 3
// baseline (244.044 us; speedup 1.0000x reference)
//
#include <hip/hip_runtime.h>

constexpr int FRAME_LEN = 130;   // floats per frame
constexpr int HALF      = 65;    // rotation amount
constexpr int BLOCK     = 256;
constexpr int FPB       = 64;    // frames per block
constexpr int CHUNK_F   = FPB * FRAME_LEN;     // 8320 floats
constexpr int NSLOT     = CHUNK_F / 4;         // 2080 float4 slots
constexpr int KFULL     = NSLOT / BLOCK;       // 8 uniform iterations
constexpr int NTAIL     = NSLOT - KFULL * BLOCK; // 32 tail slots

typedef float f4 __attribute__((ext_vector_type(4)));

// floor(idx/130), valid for idx < 262144  (m = ceil(2^24/130) = 129056, e = 64)
__device__ __forceinline__ int div130(int idx) {
    return (int)(((unsigned)idx * 129056u) >> 24);
}

// One output float4 slot: gather 4 floats with per-frame rotation, NT store.
// r0 = idx - fl*130 is always even, so only element pair {2,3} can straddle
// a frame boundary (exactly when r0 == 128).
__device__ __forceinline__ void do_slot(const float* __restrict__ Xb,
                                        float* __restrict__ Ob,
                                        const int* __restrict__ s_rot,
                                        int i, int fl, int r0, int fB) {
    int j2 = r0 + 2, fB2 = fB, flB = fl;
    if (j2 >= FRAME_LEN) { j2 -= FRAME_LEN; fB2 += FRAME_LEN; flB = fl + 1; }
    const int j3 = j2 + 1;                   // never wraps independently
    const int rotA = s_rot[fl];              // wave-broadcast LDS reads
    const int rotB = s_rot[flB];
    int s0 = r0 + rotA;     if (s0 >= FRAME_LEN) s0 -= FRAME_LEN;
    int s1 = r0 + 1 + rotA; if (s1 >= FRAME_LEN) s1 -= FRAME_LEN;
    int s2 = j2 + rotB;     if (s2 >= FRAME_LEN) s2 -= FRAME_LEN;
    int s3 = j3 + rotB;     if (s3 >= FRAME_LEN) s3 -= FRAME_LEN;
    f4 v;
    v.x = Xb[fB + s0];
    v.y = Xb[fB + s1];
    v.z = Xb[fB2 + s2];
    v.w = Xb[fB2 + s3];
    __builtin_nontemporal_store(v, (f4*)Ob + i);
}

__global__ __launch_bounds__(BLOCK, 8)   // 8 waves/SIMD -> 8 blocks/CU
void hand_sorter_kernel(const float* __restrict__ X, float* __restrict__ out,
                        int n_frames) {
    __shared__ int s_rot[FPB + 1];
    const int t = threadIdx.x;
    const long long frame0 = (long long)blockIdx.x * FPB;
    const long long rem = (long long)n_frames - frame0;
    const int frames_here = rem < (long long)FPB ? (int)rem : FPB;
    const long long base = frame0 * (long long)FRAME_LEN;
    const float* __restrict__ Xb = X + base;
    float* __restrict__ Ob = out + base;

    // ---- Phase 1: per-frame rotation offset (0 = keep, 65 = swap) ----
    if (t < frames_here) {
        const float* fr = Xb + t * FRAME_LEN;
        const float h0 = fr[0];
        const float p0 = fr[1];
        const float h1 = fr[HALF];
        const float p1 = fr[HALF + 1];
        const bool nan0 = (h0 != h0);
        const bool nan1 = (h1 != h1);
        const bool no_nan = !nan0 && !nan1;
        const bool eq = (h0 == h1);
        const bool skip =
            (h1 > h0) ||
            (nan0 && nan1) ||
            (nan0 && (h1 == 1.0f)) ||
            (nan1 && (h0 == 0.0f)) ||
            (no_nan && eq && (h0 == 0.0f) && (p0 > p1)) ||
            (no_nan && eq && (h0 == 1.0f) && (p0 < p1));
        s_rot[t] = skip ? 0 : HALF;
    }
    __syncthreads();   // only 4 tiny loads precede this -> short drain

    // ---- Phase 2: streaming gather, identity float4 NT stores ----
    if (frames_here == FPB) {
        int idx = 4 * t;
        int fl = div130(idx);
        int r0 = idx - fl * FRAME_LEN;
        int fB = fl * FRAME_LEN;
#pragma unroll 4
        for (int k = 0; k < KFULL; ++k) {
            do_slot(Xb, Ob, s_rot, t + k * BLOCK, fl, r0, fB);
            // advance slot index by 256 -> idx by 1024 = 7 frames + 114 floats
            r0 += 114; fl += 7; fB += 7 * FRAME_LEN;
            if (r0 >= FRAME_LEN) { r0 -= FRAME_LEN; ++fl; fB += FRAME_LEN; }
        }
        if (t < NTAIL) {
            const int i = KFULL * BLOCK + t;
            const int id2 = 4 * i;
            const int f2 = div130(id2);
            do_slot(Xb, Ob, s_rot, i, f2, id2 - f2 * FRAME_LEN, f2 * FRAME_LEN);
        }
    } else {
        // generic partial-block fallback (unused when n_frames % FPB == 0)
        const int nf = frames_here * FRAME_LEN;
        for (int idx = t; idx < nf; idx += BLOCK) {
            const int fl = div130(idx);
            const int jj = idx - fl * FRAME_LEN;
            int sj = jj + s_rot[fl];
            if (sj >= FRAME_LEN) sj -= FRAME_LEN;
            Ob[idx] = Xb[fl * FRAME_LEN + sj];
        }
    }
}

extern "C" void kernel_launch(void* const* d_in, const int* in_sizes, int n_in,
                              void* d_out, int out_size, void* d_ws, size_t ws_size,
                              hipStream_t stream) {
    const float* X = (const float*)d_in[0];
    float* out = (float*)d_out;
    const int n_frames = in_sizes[0] / FRAME_LEN;   // 262144
    const int n_blocks = (n_frames + FPB - 1) / FPB;
    hand_sorter_kernel<<<n_blocks, BLOCK, 0, stream>>>(X, out, n_frames);
}